// Round 3
// baseline (683.136 us; speedup 1.0000x reference)
//
#include <hip/hip_runtime.h>
#include <hip/hip_bf16.h>
#include <math.h>

// ---------------------------------------------------------------------------
// DeepDCNN: emb-gather -> 4x [grouped full-conv + pair-fold + ordered top-k +
// tanh] -> FC.  All fp32.  Top-k = wave-level radix select with 4-way
// bank-spread replicated LDS histograms (cuts same-address atomic serialization).
// ---------------------------------------------------------------------------

#define WAVE_FENCE() __asm__ volatile("s_waitcnt lgkmcnt(0)" ::: "memory")

__device__ __forceinline__ unsigned f2ord(float f) {
    unsigned u = __float_as_uint(f);
    return (u & 0x80000000u) ? ~u : (u | 0x80000000u);
}

// tanh via exp: 1 - 2/(e^{2x}+1).  ~1e-7 abs error; selection keys are
// computed pre-tanh so ordering is unaffected.
__device__ __forceinline__ float tanh_fast(float x) {
    float e = __expf(2.f * x);
    return 1.f - 2.f / (e + 1.f);
}

// Wave-level exact top-k (order-preserving, stable ties = earliest kept).
// Lane holds contiguous chunk [lane*CH, lane*CH+len) in registers.
// hist = per-wave 1024-int LDS scratch, layout hist[bin*4 + copy] (4 copies
// spread over 4 banks -> atomic contention / 4).
template<int CH>
__device__ void wave_select(const unsigned* keys, const float* vals,
                            int len, int k, int* hist,
                            float* __restrict__ out)
{
    const int lane = threadIdx.x & 63;
    const int copy = lane & 3;
    unsigned prefix = 0;
    int remaining = k;
    #pragma unroll
    for (int shift = 24; shift >= 0; shift -= 8) {
        {   // zero 1024 ints: 4 x int4 per lane
            int4 z = make_int4(0, 0, 0, 0);
            int4* h4 = (int4*)hist;
            h4[lane] = z; h4[lane + 64] = z; h4[lane + 128] = z; h4[lane + 192] = z;
        }
        WAVE_FENCE();
        const unsigned himask = (shift == 24) ? 0u : (0xFFFFFFFFu << (shift + 8));
        #pragma unroll
        for (int i = 0; i < CH; ++i) {
            if (i < len && (keys[i] & himask) == prefix)
                atomicAdd(&hist[(((keys[i] >> shift) & 255u) << 2) | copy], 1);
        }
        WAVE_FENCE();
        // lane owns bins 4*lane .. 4*lane+3; sum the 4 copies of each
        const int4* h4 = (const int4*)hist;
        int4 a = h4[4 * lane + 0];
        int4 bb = h4[4 * lane + 1];
        int4 c = h4[4 * lane + 2];
        int4 d = h4[4 * lane + 3];
        int h0 = a.x + a.y + a.z + a.w;
        int h1 = bb.x + bb.y + bb.z + bb.w;
        int h2 = c.x + c.y + c.z + c.w;
        int h3 = d.x + d.y + d.z + d.w;
        int s = h0 + h1 + h2 + h3;
        // wave suffix-sum: U = sum over lanes >= lane
        int U = s;
        #pragma unroll
        for (int off = 1; off < 64; off <<= 1) {
            int tmp = __shfl_down(U, off, 64);
            if (lane + off < 64) U += tmp;
        }
        int base = U - s;                 // sum over lanes > lane
        int S3 = base + h3;               // S(b) = sum_{b' >= b} hist[b']
        int S2 = S3 + h2;
        int S1 = S2 + h1;
        int S0 = S1 + h0;
        int cand = -1;                    // max bin with S(bin) >= remaining
        if      (S3 >= remaining) cand = 4 * lane + 3;
        else if (S2 >= remaining) cand = 4 * lane + 2;
        else if (S1 >= remaining) cand = 4 * lane + 1;
        else if (S0 >= remaining) cand = 4 * lane;
        #pragma unroll
        for (int off = 1; off < 64; off <<= 1)
            cand = max(cand, __shfl_xor(cand, off, 64));
        const int B = cand;               // wave-uniform selected bin
        const int bi = B & 3, owner = B >> 2;
        int SB_l = (bi == 3) ? S3 : (bi == 2) ? S2 : (bi == 1) ? S1 : S0;
        int hB_l = (bi == 3) ? h3 : (bi == 2) ? h2 : (bi == 1) ? h1 : h0;
        int SB = __shfl(SB_l, owner, 64);
        int hB = __shfl(hB_l, owner, 64);
        remaining -= (SB - hB);           // count strictly above bin B
        prefix |= ((unsigned)B) << shift;
    }
    const unsigned T = prefix;            // exact key of k-th largest
    const int needTies = remaining;       // # of ==T to keep (earliest)

    int g = 0, e = 0;
    #pragma unroll
    for (int i = 0; i < CH; ++i)
        if (i < len) { g += (keys[i] > T); e += (keys[i] == T); }
    int pg = g, pe = e;
    #pragma unroll
    for (int off = 1; off < 64; off <<= 1) {
        int tg = __shfl_up(pg, off, 64);
        int te = __shfl_up(pe, off, 64);
        if (lane >= off) { pg += tg; pe += te; }
    }
    const int gtBefore = pg - g, eqBefore = pe - e;
    int gRun = 0, eRun = 0;
    #pragma unroll
    for (int i = 0; i < CH; ++i) {
        if (i < len) {
            unsigned key = keys[i];
            if (key > T) {
                int cap = eqBefore + eRun; if (cap > needTies) cap = needTies;
                out[gtBefore + gRun + cap] = tanh_fast(vals[i]);
                ++gRun;
            } else if (key == T) {
                int eIdx = eqBefore + eRun;
                if (eIdx < needTies) out[gtBefore + gRun + eIdx] = tanh_fast(vals[i]);
                ++eRun;
            }
        }
    }
}

// ---------------------------------------------------------------------------
// Layer 1 fused: emb gather + pair conv (IPG=1,K=7) + fold + select + tanh.
// grid (32 j, 64 b, 2 half), block 320 = 5 waves; wave w -> f = half*5 + w.
// ---------------------------------------------------------------------------
__global__ __launch_bounds__(320) void layer1_fused(
    const int* __restrict__ tokens, const float* __restrict__ emb,
    const float* __restrict__ W1, const float* __restrict__ B1,
    float* __restrict__ Z1)
{
    const int j = blockIdx.x;       // 0..31 pair-group
    const int b = blockIdx.y;       // 0..63
    const int half = blockIdx.z;    // 0..1
    const int t = threadIdx.x;
    const int w = t >> 6, lane = t & 63;
    const int f = half * 5 + w;     // 0..9

    __shared__ float xr[2][1036];
    __shared__ __align__(16) int hist[5][1024];

    const float2* emb2 = (const float2*)emb;
    for (int i = t; i < 1036; i += 320) {
        int s = i - 6;
        float a = 0.f, c = 0.f;
        if (s >= 0 && s < 1024) {
            int tok = tokens[b * 1024 + s];
            float2 v = emb2[(size_t)tok * 32 + j];
            a = v.x; c = v.y;
        }
        xr[0][i] = a;
        xr[1][i] = c;
    }
    __syncthreads();

    const int beg = lane * 17;
    const int len = max(0, min(17, 1030 - beg));
    float x0[23], x1[23];
    #pragma unroll
    for (int i = 0; i < 23; ++i)
        if (i < len + 6) { x0[i] = xr[0][beg + i]; x1[i] = xr[1][beg + i]; }

    float wa[7], wb[7];
    #pragma unroll
    for (int k2 = 0; k2 < 7; ++k2) {
        wa[k2] = W1[(2 * j * 10 + f) * 7 + k2];
        wb[k2] = W1[((2 * j + 1) * 10 + f) * 7 + k2];
    }
    float bias = B1[2 * j * 10 + f] + B1[(2 * j + 1) * 10 + f];

    float vals[17]; unsigned keys[17];
    #pragma unroll
    for (int i = 0; i < 17; ++i) {
        if (i < len) {
            float acc = bias;
            #pragma unroll
            for (int k2 = 0; k2 < 7; ++k2)
                acc += x0[i + k2] * wa[k2] + x1[i + k2] * wb[k2];
            vals[i] = acc; keys[i] = f2ord(acc);
        }
    }
    wave_select<17>(keys, vals, len, 768, hist[w],
                    Z1 + ((size_t)(b * 320 + j * 10 + f)) * 768);
}

// ---------------------------------------------------------------------------
// Generic grouped conv + fold (layers 2-4), LDS-tiled.
// ---------------------------------------------------------------------------
template <int IPG, int NF, int K, int TILE>
__global__ __launch_bounds__(256) void conv_fold_kernel(
    const float* __restrict__ X, const float* __restrict__ W,
    const float* __restrict__ Bias, float* __restrict__ Y,
    int Cin, int S, int Sout, int Cfold)
{
    const int t  = threadIdx.x;
    const int s0 = blockIdx.x * TILE;
    const int j  = blockIdx.y;
    const int b  = blockIdx.z;

    constexpr int WIDTH = TILE + K - 1;
    __shared__ float xs[2 * IPG][WIDTH];
    __shared__ float wt[2 * NF * IPG * K];
    __shared__ float bsum[NF];

    const float* Xb = X + ((size_t)b * Cin + (size_t)(2 * j) * IPG) * S;
    for (int idx = t; idx < 2 * IPG * WIDTH; idx += 256) {
        int r = idx / WIDTH, p = idx % WIDTH;
        int sg = s0 + p - (K - 1);
        xs[r][p] = (sg >= 0 && sg < S) ? Xb[(size_t)r * S + sg] : 0.f;
    }
    const float* Wb = W + (size_t)(2 * j * NF) * IPG * K;
    for (int idx = t; idx < 2 * NF * IPG * K; idx += 256) wt[idx] = Wb[idx];
    if (t < NF) bsum[t] = Bias[2 * j * NF + t] + Bias[(2 * j + 1) * NF + t];
    __syncthreads();

    const int s = s0 + t;
    if (s < Sout) {
        for (int f = 0; f < NF; ++f) {
            float acc = bsum[f];
            #pragma unroll
            for (int h = 0; h < 2; ++h) {
                const float* wr = &wt[(h * NF + f) * IPG * K];
                #pragma unroll
                for (int c = 0; c < IPG; ++c) {
                    #pragma unroll
                    for (int k = 0; k < K; ++k)
                        acc += xs[h * IPG + c][t + k] * wr[c * K + k];
                }
            }
            Y[((size_t)b * Cfold + j * NF + f) * (size_t)Sout + s] = acc;
        }
    }
}

// ---------------------------------------------------------------------------
// Wave-per-row select + tanh.  block 256 = 4 waves = 4 rows.
// ---------------------------------------------------------------------------
template<int CH>
__global__ __launch_bounds__(256) void select_kernel(
    const float* __restrict__ Y, float* __restrict__ Z, int n, int k)
{
    __shared__ __align__(16) int hist[4][1024];
    const int w = threadIdx.x >> 6, lane = threadIdx.x & 63;
    const int row = blockIdx.x * 4 + w;
    const float* src = Y + (size_t)row * n;
    const int beg = lane * CH;
    const int len = max(0, min(CH, n - beg));
    float vals[CH]; unsigned keys[CH];
    #pragma unroll
    for (int i = 0; i < CH; ++i)
        if (i < len) { float v = src[beg + i]; vals[i] = v; keys[i] = f2ord(v); }
    wave_select<CH>(keys, vals, len, k, hist[w], Z + (size_t)row * k);
}

// ---------------------------------------------------------------------------
// FC: (64,352) @ (6,352)^T + b
// ---------------------------------------------------------------------------
__global__ __launch_bounds__(192) void fc_kernel(
    const float* __restrict__ Z, const float* __restrict__ Wf,
    const float* __restrict__ bf, float* __restrict__ out)
{
    int g = blockIdx.x * blockDim.x + threadIdx.x;
    if (g >= 64 * 6) return;
    int b = g / 6, c = g % 6;
    float acc = bf[c];
    const float* zr = Z + b * 352;
    const float* wr = Wf + c * 352;
    for (int i = 0; i < 352; ++i) acc += zr[i] * wr[i];
    out[g] = acc;
}

extern "C" void kernel_launch(void* const* d_in, const int* in_sizes, int n_in,
                              void* d_out, int out_size, void* d_ws, size_t ws_size,
                              hipStream_t stream)
{
    const int*   tokens = (const int*)  d_in[0];
    const float* emb    = (const float*)d_in[1];
    const float* w1     = (const float*)d_in[2];
    const float* b1     = (const float*)d_in[3];
    const float* w2     = (const float*)d_in[4];
    const float* b2     = (const float*)d_in[5];
    const float* w3     = (const float*)d_in[6];
    const float* b3     = (const float*)d_in[7];
    const float* w4     = (const float*)d_in[8];
    const float* b4     = (const float*)d_in[9];
    const float* fcw    = (const float*)d_in[10];
    const float* fcb    = (const float*)d_in[11];
    float* out = (float*)d_out;
    float* ws  = (float*)d_ws;

    // workspace layout (floats):
    //  Z1 [0,        15728640)   64*320*768
    //  Y2 [15728640, 26796032)   64*224*772   (peak ~107 MB)
    //  Z2 [0,         7340032)   64*224*512
    //  Y3 [7340032,  12095488)   64*144*516
    //  Z3 [0,         2359296)   64*144*256
    //  Y4 [2359296,   3812352)   64*88*258
    //  Z4 [3812352,   3834880)   64*88*4
    float* Z1 = ws;
    float* Y2 = ws + 15728640;
    float* Z2 = ws;
    float* Y3 = ws + 7340032;
    float* Z3 = ws;
    float* Y4 = ws + 2359296;
    float* Z4 = ws + 3812352;

    layer1_fused<<<dim3(32, 64, 2), 320, 0, stream>>>(tokens, emb, w1, b1, Z1);

    conv_fold_kernel<10, 14, 5, 256><<<dim3(4, 16, 64), 256, 0, stream>>>(
        Z1, w2, b2, Y2, 320, 768, 772, 224);
    select_kernel<13><<<64 * 224 / 4, 256, 0, stream>>>(Y2, Z2, 772, 512);

    conv_fold_kernel<14, 18, 5, 256><<<dim3(3, 8, 64), 256, 0, stream>>>(
        Z2, w3, b3, Y3, 224, 512, 516, 144);
    select_kernel<9><<<64 * 144 / 4, 256, 0, stream>>>(Y3, Z3, 516, 256);

    conv_fold_kernel<18, 22, 3, 256><<<dim3(2, 4, 64), 256, 0, stream>>>(
        Z3, w4, b4, Y4, 144, 256, 258, 88);
    select_kernel<5><<<64 * 88 / 4, 256, 0, stream>>>(Y4, Z4, 258, 4);

    fc_kernel<<<2, 192, 0, stream>>>(Z4, fcw, fcb, out);
}

// Round 4
// 598.249 us; speedup vs baseline: 1.1419x; 1.1419x over previous
//
#include <hip/hip_runtime.h>
#include <hip/hip_bf16.h>
#include <math.h>

// ---------------------------------------------------------------------------
// DeepDCNN: emb-gather -> 4x [grouped full-conv + pair-fold + ordered top-k +
// tanh] -> FC.  All fp32.  Top-k = wave-level radix select, register-resident
// keys (launch_bounds chosen so the key arrays NEVER spill to scratch).
// ---------------------------------------------------------------------------

#define WAVE_FENCE() __asm__ volatile("s_waitcnt lgkmcnt(0)" ::: "memory")

__device__ __forceinline__ unsigned f2ord(float f) {
    unsigned u = __float_as_uint(f);
    return (u & 0x80000000u) ? ~u : (u | 0x80000000u);
}
// inverse of f2ord
__device__ __forceinline__ float ord2f(unsigned key) {
    unsigned u = (key & 0x80000000u) ? (key & 0x7fffffffu) : ~key;
    return __uint_as_float(u);
}
// tanh via exp: 1 - 2/(e^{2x}+1).  ~1e-7 abs error; selection keys are
// pre-tanh so ordering is unaffected.
__device__ __forceinline__ float tanh_fast(float x) {
    float e = __expf(2.f * x);
    return 1.f - 2.f / (e + 1.f);
}

// Wave-level exact top-k (order-preserving, stable ties = earliest kept).
// Lane holds contiguous chunk [lane*CH, lane*CH+len) as order-keys in regs.
// hist = per-wave 1024-int LDS scratch, layout hist[bin*4 + copy].
// Writes tanh(value) of kept elements, original order, to out[0..k).
template<int CH>
__device__ void wave_select(const unsigned* keys, int len, int k, int* hist,
                            float* __restrict__ out)
{
    const int lane = threadIdx.x & 63;
    const int copy = lane & 3;
    unsigned prefix = 0;
    int remaining = k;
    #pragma unroll
    for (int shift = 24; shift >= 0; shift -= 8) {
        {   // zero 1024 ints: 4 x int4 per lane
            int4 z = make_int4(0, 0, 0, 0);
            int4* h4 = (int4*)hist;
            h4[lane] = z; h4[lane + 64] = z; h4[lane + 128] = z; h4[lane + 192] = z;
        }
        WAVE_FENCE();
        const unsigned himask = (shift == 24) ? 0u : (0xFFFFFFFFu << (shift + 8));
        #pragma unroll
        for (int i = 0; i < CH; ++i) {
            if (i < len && (keys[i] & himask) == prefix)
                atomicAdd(&hist[(((keys[i] >> shift) & 255u) << 2) | copy], 1);
        }
        WAVE_FENCE();
        // lane owns bins 4*lane .. 4*lane+3; sum the 4 copies of each
        const int4* h4 = (const int4*)hist;
        int4 a  = h4[4 * lane + 0];
        int4 bb = h4[4 * lane + 1];
        int4 c  = h4[4 * lane + 2];
        int4 d  = h4[4 * lane + 3];
        int h0 = a.x + a.y + a.z + a.w;
        int h1 = bb.x + bb.y + bb.z + bb.w;
        int h2 = c.x + c.y + c.z + c.w;
        int h3 = d.x + d.y + d.z + d.w;
        int s = h0 + h1 + h2 + h3;
        // wave suffix-sum: U = sum over lanes >= lane
        int U = s;
        #pragma unroll
        for (int off = 1; off < 64; off <<= 1) {
            int tmp = __shfl_down(U, off, 64);
            if (lane + off < 64) U += tmp;
        }
        int base = U - s;                 // sum over lanes > lane
        int S3 = base + h3;               // S(b) = sum_{b' >= b} hist[b']
        int S2 = S3 + h2;
        int S1 = S2 + h1;
        int S0 = S1 + h0;
        int cand = -1;                    // max bin with S(bin) >= remaining
        if      (S3 >= remaining) cand = 4 * lane + 3;
        else if (S2 >= remaining) cand = 4 * lane + 2;
        else if (S1 >= remaining) cand = 4 * lane + 1;
        else if (S0 >= remaining) cand = 4 * lane;
        #pragma unroll
        for (int off = 1; off < 64; off <<= 1)
            cand = max(cand, __shfl_xor(cand, off, 64));
        const int B = cand;               // wave-uniform selected bin
        const int bi = B & 3, owner = B >> 2;
        int SB_l = (bi == 3) ? S3 : (bi == 2) ? S2 : (bi == 1) ? S1 : S0;
        int hB_l = (bi == 3) ? h3 : (bi == 2) ? h2 : (bi == 1) ? h1 : h0;
        int SB = __shfl(SB_l, owner, 64);
        int hB = __shfl(hB_l, owner, 64);
        remaining -= (SB - hB);           // count strictly above bin B
        prefix |= ((unsigned)B) << shift;
    }
    const unsigned T = prefix;            // exact key of k-th largest
    const int needTies = remaining;       // # of ==T to keep (earliest)

    int g = 0, e = 0;
    #pragma unroll
    for (int i = 0; i < CH; ++i)
        if (i < len) { g += (keys[i] > T); e += (keys[i] == T); }
    int pg = g, pe = e;
    #pragma unroll
    for (int off = 1; off < 64; off <<= 1) {
        int tg = __shfl_up(pg, off, 64);
        int te = __shfl_up(pe, off, 64);
        if (lane >= off) { pg += tg; pe += te; }
    }
    const int gtBefore = pg - g, eqBefore = pe - e;
    int gRun = 0, eRun = 0;
    #pragma unroll
    for (int i = 0; i < CH; ++i) {
        if (i < len) {
            unsigned key = keys[i];
            if (key > T) {
                int cap = eqBefore + eRun; if (cap > needTies) cap = needTies;
                out[gtBefore + gRun + cap] = tanh_fast(ord2f(key));
                ++gRun;
            } else if (key == T) {
                int eIdx = eqBefore + eRun;
                if (eIdx < needTies) out[gtBefore + gRun + eIdx] = tanh_fast(ord2f(key));
                ++eRun;
            }
        }
    }
}

// ---------------------------------------------------------------------------
// Layer 1 fused: emb gather + pair conv (IPG=1,K=7) + fold + select + tanh.
// grid (32 j, 64 b), block 320 = 5 waves; wave w -> f = w, w+5.
// launch_bounds min-waves=1: VGPR cap 512 so x-window + keys stay in regs.
// ---------------------------------------------------------------------------
__global__ __launch_bounds__(320, 1) void layer1_fused(
    const int* __restrict__ tokens, const float* __restrict__ emb,
    const float* __restrict__ W1, const float* __restrict__ B1,
    float* __restrict__ Z1)
{
    const int j = blockIdx.x;       // 0..31 pair-group
    const int b = blockIdx.y;       // 0..63
    const int t = threadIdx.x;
    const int w = t >> 6, lane = t & 63;

    __shared__ float xr[2][1036];
    __shared__ __align__(16) int hist[5][1024];

    const float2* emb2 = (const float2*)emb;
    for (int i = t; i < 1036; i += 320) {
        int s = i - 6;
        float a = 0.f, c = 0.f;
        if (s >= 0 && s < 1024) {
            int tok = tokens[b * 1024 + s];
            float2 v = emb2[(size_t)tok * 32 + j];
            a = v.x; c = v.y;
        }
        xr[0][i] = a;
        xr[1][i] = c;
    }
    __syncthreads();

    const int beg = lane * 17;
    const int len = max(0, min(17, 1030 - beg));
    float x0[23], x1[23];
    #pragma unroll
    for (int i = 0; i < 23; ++i)
        if (i < len + 6) { x0[i] = xr[0][beg + i]; x1[i] = xr[1][beg + i]; }

    for (int f = w; f < 10; f += 5) {
        float wa[7], wb[7];
        #pragma unroll
        for (int k2 = 0; k2 < 7; ++k2) {
            wa[k2] = W1[(2 * j * 10 + f) * 7 + k2];
            wb[k2] = W1[((2 * j + 1) * 10 + f) * 7 + k2];
        }
        float bias = B1[2 * j * 10 + f] + B1[(2 * j + 1) * 10 + f];
        unsigned keys[17];
        #pragma unroll
        for (int i = 0; i < 17; ++i) {
            if (i < len) {
                float acc = bias;
                #pragma unroll
                for (int k2 = 0; k2 < 7; ++k2)
                    acc += x0[i + k2] * wa[k2] + x1[i + k2] * wb[k2];
                keys[i] = f2ord(acc);
            }
        }
        wave_select<17>(keys, len, 768, hist[w],
                        Z1 + ((size_t)(b * 320 + j * 10 + f)) * 768);
    }
}

// ---------------------------------------------------------------------------
// Grouped conv + fold (layers 2-4).  Register accumulators acc[NF] +
// K-register sliding window; weights/bias read with block-uniform indices
// only -> scalarized to s_load (SGPR FMA operands), no LDS weight reads.
// ---------------------------------------------------------------------------
template <int IPG, int NF, int K, int TILE>
__global__ __launch_bounds__(TILE, 2) void conv_fold_kernel(
    const float* __restrict__ X, const float* __restrict__ W,
    const float* __restrict__ Bias, float* __restrict__ Y,
    int Cin, int S, int Sout, int Cfold)
{
    const int t  = threadIdx.x;
    const int s0 = blockIdx.x * TILE;
    const int j  = blockIdx.y;
    const int b  = blockIdx.z;

    constexpr int WIDTH = TILE + K - 1;
    __shared__ float xs[2 * IPG][WIDTH];

    const float* Xb = X + ((size_t)b * Cin + (size_t)(2 * j) * IPG) * S;
    #pragma unroll 4
    for (int r = 0; r < 2 * IPG; ++r) {
        for (int p = t; p < WIDTH; p += TILE) {
            int sg = s0 + p - (K - 1);
            xs[r][p] = (sg >= 0 && sg < S) ? Xb[(size_t)r * S + sg] : 0.f;
        }
    }
    __syncthreads();

    float acc[NF];
    #pragma unroll
    for (int f = 0; f < NF; ++f)
        acc[f] = Bias[2 * j * NF + f] + Bias[(2 * j + 1) * NF + f];

    const float* Wj = W + (size_t)(2 * j * NF) * IPG * K;
    #pragma unroll 2
    for (int h = 0; h < 2; ++h) {
        for (int c = 0; c < IPG; ++c) {
            float win[K];
            #pragma unroll
            for (int k2 = 0; k2 < K; ++k2)
                win[k2] = xs[h * IPG + c][t + k2];
            #pragma unroll
            for (int f = 0; f < NF; ++f) {
                const float* wf = Wj + ((h * NF + f) * IPG + c) * (size_t)K;
                #pragma unroll
                for (int k2 = 0; k2 < K; ++k2)
                    acc[f] += win[k2] * wf[k2];
            }
        }
    }

    const int s = s0 + t;
    if (s < Sout) {
        #pragma unroll
        for (int f = 0; f < NF; ++f)
            Y[((size_t)b * Cfold + j * NF + f) * (size_t)Sout + s] = acc[f];
    }
}

// ---------------------------------------------------------------------------
// Wave-per-row select + tanh.  block 256 = 4 waves = 4 rows.
// ---------------------------------------------------------------------------
template<int CH>
__global__ __launch_bounds__(256, 2) void select_kernel(
    const float* __restrict__ Y, float* __restrict__ Z, int n, int k)
{
    __shared__ __align__(16) int hist[4][1024];
    const int w = threadIdx.x >> 6, lane = threadIdx.x & 63;
    const int row = blockIdx.x * 4 + w;
    const float* src = Y + (size_t)row * n;
    const int beg = lane * CH;
    const int len = max(0, min(CH, n - beg));
    unsigned keys[CH];
    #pragma unroll
    for (int i = 0; i < CH; ++i)
        if (i < len) keys[i] = f2ord(src[beg + i]);
    wave_select<CH>(keys, len, k, hist[w], Z + (size_t)row * k);
}

// ---------------------------------------------------------------------------
// FC: (64,352) @ (6,352)^T + b
// ---------------------------------------------------------------------------
__global__ __launch_bounds__(192) void fc_kernel(
    const float* __restrict__ Z, const float* __restrict__ Wf,
    const float* __restrict__ bf, float* __restrict__ out)
{
    int g = blockIdx.x * blockDim.x + threadIdx.x;
    if (g >= 64 * 6) return;
    int b = g / 6, c = g % 6;
    float acc = bf[c];
    const float* zr = Z + b * 352;
    const float* wr = Wf + c * 352;
    for (int i = 0; i < 352; ++i) acc += zr[i] * wr[i];
    out[g] = acc;
}

extern "C" void kernel_launch(void* const* d_in, const int* in_sizes, int n_in,
                              void* d_out, int out_size, void* d_ws, size_t ws_size,
                              hipStream_t stream)
{
    const int*   tokens = (const int*)  d_in[0];
    const float* emb    = (const float*)d_in[1];
    const float* w1     = (const float*)d_in[2];
    const float* b1     = (const float*)d_in[3];
    const float* w2     = (const float*)d_in[4];
    const float* b2     = (const float*)d_in[5];
    const float* w3     = (const float*)d_in[6];
    const float* b3     = (const float*)d_in[7];
    const float* w4     = (const float*)d_in[8];
    const float* b4     = (const float*)d_in[9];
    const float* fcw    = (const float*)d_in[10];
    const float* fcb    = (const float*)d_in[11];
    float* out = (float*)d_out;
    float* ws  = (float*)d_ws;

    // workspace layout (floats):
    //  Z1 [0,        15728640)   64*320*768
    //  Y2 [15728640, 26796032)   64*224*772   (peak ~107 MB)
    //  Z2 [0,         7340032)   64*224*512
    //  Y3 [7340032,  12095488)   64*144*516
    //  Z3 [0,         2359296)   64*144*256
    //  Y4 [2359296,   3812352)   64*88*258
    //  Z4 [3812352,   3834880)   64*88*4
    float* Z1 = ws;
    float* Y2 = ws + 15728640;
    float* Z2 = ws;
    float* Y3 = ws + 7340032;
    float* Z3 = ws;
    float* Y4 = ws + 2359296;
    float* Z4 = ws + 3812352;

    layer1_fused<<<dim3(32, 64), 320, 0, stream>>>(tokens, emb, w1, b1, Z1);

    conv_fold_kernel<10, 14, 5, 256><<<dim3(4, 16, 64), 256, 0, stream>>>(
        Z1, w2, b2, Y2, 320, 768, 772, 224);
    select_kernel<13><<<64 * 224 / 4, 256, 0, stream>>>(Y2, Z2, 772, 512);

    conv_fold_kernel<14, 18, 5, 256><<<dim3(3, 8, 64), 256, 0, stream>>>(
        Z2, w3, b3, Y3, 224, 512, 516, 144);
    select_kernel<9><<<64 * 144 / 4, 256, 0, stream>>>(Y3, Z3, 516, 256);

    conv_fold_kernel<18, 22, 3, 256><<<dim3(2, 4, 64), 256, 0, stream>>>(
        Z3, w4, b4, Y4, 144, 256, 258, 88);
    select_kernel<5><<<64 * 88 / 4, 256, 0, stream>>>(Y4, Z4, 258, 4);

    fc_kernel<<<2, 192, 0, stream>>>(Z4, fcw, fcb, out);
}

// Round 5
// 541.358 us; speedup vs baseline: 1.2619x; 1.1051x over previous
//
#include <hip/hip_runtime.h>
#include <hip/hip_bf16.h>
#include <math.h>

// ---------------------------------------------------------------------------
// DeepDCNN: emb-gather -> 4x [grouped full-conv + pair-fold + ordered top-k +
// tanh] -> FC.  All fp32.
// Top-k = wave-level bitwise radix select using ONLY ballot + scalar popcount
// (zero LDS, zero atomics, zero shfl): at each bit, the exact test
// "bit of k-th largest is 1" is  count(key >= p|1<<pos) >= k.
// ---------------------------------------------------------------------------

__device__ __forceinline__ unsigned f2ord(float f) {
    unsigned u = __float_as_uint(f);
    return (u & 0x80000000u) ? ~u : (u | 0x80000000u);
}
// inverse of f2ord
__device__ __forceinline__ float ord2f(unsigned key) {
    unsigned u = (key & 0x80000000u) ? (key & 0x7fffffffu) : ~key;
    return __uint_as_float(u);
}
// tanh via exp: 1 - 2/(e^{2x}+1).  Selection keys are pre-tanh, so ordering
// is unaffected.
__device__ __forceinline__ float tanh_fast(float x) {
    float e = __expf(2.f * x);
    return 1.f - 2.f / (e + 1.f);
}
// popcount of ballot bits strictly below this lane
__device__ __forceinline__ int mbcnt64(unsigned long long m) {
    return __builtin_amdgcn_mbcnt_hi((unsigned)(m >> 32),
           __builtin_amdgcn_mbcnt_lo((unsigned)m, 0u));
}

// Wave-level exact top-k (order-preserving, stable ties = earliest kept),
// matching stable lax.top_k -> sort(idx) -> gather.  Lane holds contiguous
// chunk [lane*CH, ...) as order-keys in regs; invalid slots MUST be 0
// (0 is below every real finite-float key, which is >= 0x00800000).
// Writes tanh(value) of kept elements, original order, to out[0..k).
template<int CH>
__device__ void wave_select(const unsigned* keys, int k,
                            float* __restrict__ out)
{
    // ---- exact k-th-largest key via 32-bit MSD radix, ballot counting ----
    unsigned p = 0;
    #pragma unroll 1
    for (int pos = 31; pos >= 0; --pos) {
        const unsigned t = p | (1u << pos);
        int cnt = 0;
        #pragma unroll
        for (int i = 0; i < CH; ++i)
            cnt += __popcll(__ballot(keys[i] >= t));
        if (cnt >= k) p = t;          // wave-uniform (scalar) decision
    }
    const unsigned T = p;

    // ---- stable compaction: per-lane counts + ballot/mbcnt prefix scan ----
    int g = 0, e = 0;
    #pragma unroll
    for (int i = 0; i < CH; ++i) { g += (keys[i] > T); e += (keys[i] == T); }

    int gtBefore = 0, eqBefore = 0, totG = 0;
    #pragma unroll
    for (int b = 0; b < 5; ++b) {     // CH <= 17 < 32 -> 5 bits
        unsigned long long mg = __ballot((g >> b) & 1);
        unsigned long long me = __ballot((e >> b) & 1);
        gtBefore += mbcnt64(mg) << b;
        eqBefore += mbcnt64(me) << b;
        totG     += __popcll(mg) << b;
    }
    const int needTies = k - totG;    // # of ==T to keep (earliest)

    int gRun = 0, eRun = 0;
    #pragma unroll
    for (int i = 0; i < CH; ++i) {
        unsigned key = keys[i];
        if (key > T) {
            int cap = eqBefore + eRun; if (cap > needTies) cap = needTies;
            out[gtBefore + gRun + cap] = tanh_fast(ord2f(key));
            ++gRun;
        } else if (key == T) {
            int eIdx = eqBefore + eRun;
            if (eIdx < needTies) out[gtBefore + gRun + eIdx] = tanh_fast(ord2f(key));
            ++eRun;
        }
    }
}

// ---------------------------------------------------------------------------
// Layer 1 fused: emb gather + pair conv (IPG=1,K=7) + fold + select + tanh.
// grid (32 j, 64 b), block 640 = 10 waves; wave w handles filter f = w.
// LDS = gather buffer only (8.3 KB) -> high occupancy.
// ---------------------------------------------------------------------------
__global__ __launch_bounds__(640) void layer1_fused(
    const int* __restrict__ tokens, const float* __restrict__ emb,
    const float* __restrict__ W1, const float* __restrict__ B1,
    float* __restrict__ Z1)
{
    const int j = blockIdx.x;       // 0..31 pair-group
    const int b = blockIdx.y;       // 0..63
    const int t = threadIdx.x;
    const int f = t >> 6;           // 0..9 (wave id = filter)
    const int lane = t & 63;

    __shared__ float xr[2][1036];

    const float2* emb2 = (const float2*)emb;
    for (int i = t; i < 1036; i += 640) {
        int s = i - 6;
        float a = 0.f, c = 0.f;
        if (s >= 0 && s < 1024) {
            int tok = tokens[b * 1024 + s];
            float2 v = emb2[(size_t)tok * 32 + j];
            a = v.x; c = v.y;
        }
        xr[0][i] = a;
        xr[1][i] = c;
    }
    __syncthreads();

    const int beg = lane * 17;
    const int len = max(0, min(17, 1030 - beg));

    float x0[23], x1[23];
    #pragma unroll
    for (int i = 0; i < 23; ++i)
        if (i < len + 6) { x0[i] = xr[0][beg + i]; x1[i] = xr[1][beg + i]; }

    float wa[7], wb[7];
    #pragma unroll
    for (int k2 = 0; k2 < 7; ++k2) {
        wa[k2] = W1[(2 * j * 10 + f) * 7 + k2];
        wb[k2] = W1[((2 * j + 1) * 10 + f) * 7 + k2];
    }
    const float bias = B1[2 * j * 10 + f] + B1[(2 * j + 1) * 10 + f];

    unsigned keys[17];
    #pragma unroll
    for (int i = 0; i < 17; ++i) {
        if (i < len) {
            float acc = bias;
            #pragma unroll
            for (int k2 = 0; k2 < 7; ++k2)
                acc += x0[i + k2] * wa[k2] + x1[i + k2] * wb[k2];
            keys[i] = f2ord(acc);
        } else {
            keys[i] = 0u;
        }
    }
    wave_select<17>(keys, 768,
                    Z1 + ((size_t)(b * 320 + j * 10 + f)) * 768);
}

// ---------------------------------------------------------------------------
// Grouped conv + fold (layers 2-4).  Register accumulators acc[NF] +
// K-register sliding window; weights/bias read with block-uniform indices
// only -> scalarized to s_load (SGPR FMA operands).
// ---------------------------------------------------------------------------
template <int IPG, int NF, int K, int TILE>
__global__ __launch_bounds__(TILE, 2) void conv_fold_kernel(
    const float* __restrict__ X, const float* __restrict__ W,
    const float* __restrict__ Bias, float* __restrict__ Y,
    int Cin, int S, int Sout, int Cfold)
{
    const int t  = threadIdx.x;
    const int s0 = blockIdx.x * TILE;
    const int j  = blockIdx.y;
    const int b  = blockIdx.z;

    constexpr int WIDTH = TILE + K - 1;
    __shared__ float xs[2 * IPG][WIDTH];

    const float* Xb = X + ((size_t)b * Cin + (size_t)(2 * j) * IPG) * S;
    #pragma unroll 4
    for (int r = 0; r < 2 * IPG; ++r) {
        for (int p = t; p < WIDTH; p += TILE) {
            int sg = s0 + p - (K - 1);
            xs[r][p] = (sg >= 0 && sg < S) ? Xb[(size_t)r * S + sg] : 0.f;
        }
    }
    __syncthreads();

    float acc[NF];
    #pragma unroll
    for (int f = 0; f < NF; ++f)
        acc[f] = Bias[2 * j * NF + f] + Bias[(2 * j + 1) * NF + f];

    const float* Wj = W + (size_t)(2 * j * NF) * IPG * K;
    #pragma unroll 2
    for (int h = 0; h < 2; ++h) {
        for (int c = 0; c < IPG; ++c) {
            float win[K];
            #pragma unroll
            for (int k2 = 0; k2 < K; ++k2)
                win[k2] = xs[h * IPG + c][t + k2];
            #pragma unroll
            for (int f = 0; f < NF; ++f) {
                const float* wf = Wj + ((h * NF + f) * IPG + c) * (size_t)K;
                #pragma unroll
                for (int k2 = 0; k2 < K; ++k2)
                    acc[f] += win[k2] * wf[k2];
            }
        }
    }

    const int s = s0 + t;
    if (s < Sout) {
        #pragma unroll
        for (int f = 0; f < NF; ++f)
            Y[((size_t)b * Cfold + j * NF + f) * (size_t)Sout + s] = acc[f];
    }
}

// ---------------------------------------------------------------------------
// Wave-per-row select + tanh.  block 256 = 4 waves = 4 rows.  Zero LDS.
// ---------------------------------------------------------------------------
template<int CH>
__global__ __launch_bounds__(256) void select_kernel(
    const float* __restrict__ Y, float* __restrict__ Z, int n, int k)
{
    const int w = threadIdx.x >> 6, lane = threadIdx.x & 63;
    const int row = blockIdx.x * 4 + w;
    const float* src = Y + (size_t)row * n;
    const int beg = lane * CH;
    unsigned keys[CH];
    #pragma unroll
    for (int i = 0; i < CH; ++i)
        keys[i] = (beg + i < n) ? f2ord(src[beg + i]) : 0u;
    wave_select<CH>(keys, k, Z + (size_t)row * k);
}

// ---------------------------------------------------------------------------
// FC: (64,352) @ (6,352)^T + b
// ---------------------------------------------------------------------------
__global__ __launch_bounds__(192) void fc_kernel(
    const float* __restrict__ Z, const float* __restrict__ Wf,
    const float* __restrict__ bf, float* __restrict__ out)
{
    int g = blockIdx.x * blockDim.x + threadIdx.x;
    if (g >= 64 * 6) return;
    int b = g / 6, c = g % 6;
    float acc = bf[c];
    const float* zr = Z + b * 352;
    const float* wr = Wf + c * 352;
    for (int i = 0; i < 352; ++i) acc += zr[i] * wr[i];
    out[g] = acc;
}

extern "C" void kernel_launch(void* const* d_in, const int* in_sizes, int n_in,
                              void* d_out, int out_size, void* d_ws, size_t ws_size,
                              hipStream_t stream)
{
    const int*   tokens = (const int*)  d_in[0];
    const float* emb    = (const float*)d_in[1];
    const float* w1     = (const float*)d_in[2];
    const float* b1     = (const float*)d_in[3];
    const float* w2     = (const float*)d_in[4];
    const float* b2     = (const float*)d_in[5];
    const float* w3     = (const float*)d_in[6];
    const float* b3     = (const float*)d_in[7];
    const float* w4     = (const float*)d_in[8];
    const float* b4     = (const float*)d_in[9];
    const float* fcw    = (const float*)d_in[10];
    const float* fcb    = (const float*)d_in[11];
    float* out = (float*)d_out;
    float* ws  = (float*)d_ws;

    // workspace layout (floats):
    //  Z1 [0,        15728640)   64*320*768
    //  Y2 [15728640, 26796032)   64*224*772   (peak ~107 MB)
    //  Z2 [0,         7340032)   64*224*512
    //  Y3 [7340032,  12095488)   64*144*516
    //  Z3 [0,         2359296)   64*144*256
    //  Y4 [2359296,   3812352)   64*88*258
    //  Z4 [3812352,   3834880)   64*88*4
    float* Z1 = ws;
    float* Y2 = ws + 15728640;
    float* Z2 = ws;
    float* Y3 = ws + 7340032;
    float* Z3 = ws;
    float* Y4 = ws + 2359296;
    float* Z4 = ws + 3812352;

    layer1_fused<<<dim3(32, 64), 640, 0, stream>>>(tokens, emb, w1, b1, Z1);

    conv_fold_kernel<10, 14, 5, 256><<<dim3(4, 16, 64), 256, 0, stream>>>(
        Z1, w2, b2, Y2, 320, 768, 772, 224);
    select_kernel<13><<<64 * 224 / 4, 256, 0, stream>>>(Y2, Z2, 772, 512);

    conv_fold_kernel<14, 18, 5, 256><<<dim3(3, 8, 64), 256, 0, stream>>>(
        Z2, w3, b3, Y3, 224, 512, 516, 144);
    select_kernel<9><<<64 * 144 / 4, 256, 0, stream>>>(Y3, Z3, 516, 256);

    conv_fold_kernel<18, 22, 3, 256><<<dim3(2, 4, 64), 256, 0, stream>>>(
        Z3, w4, b4, Y4, 144, 256, 258, 88);
    select_kernel<5><<<64 * 88 / 4, 256, 0, stream>>>(Y4, Z4, 258, 4);

    fc_kernel<<<2, 192, 0, stream>>>(Z4, fcw, fcb, out);
}

// Round 6
// 411.168 us; speedup vs baseline: 1.6615x; 1.3166x over previous
//
#include <hip/hip_runtime.h>
#include <hip/hip_bf16.h>
#include <math.h>

// ---------------------------------------------------------------------------
// DeepDCNN: emb-gather -> 4x [grouped full-conv + pair-fold + ordered top-k +
// tanh] -> FC.  All fp32.
// Top-k = wave-level bitwise radix select using ONLY ballot + scalar popcount
// (zero LDS, zero atomics, zero shfl).  Layers 2-4 fully fused:
// conv+fold+select+tanh in one kernel, pre-select activations never hit HBM.
// ---------------------------------------------------------------------------

__device__ __forceinline__ unsigned f2ord(float f) {
    unsigned u = __float_as_uint(f);
    return (u & 0x80000000u) ? ~u : (u | 0x80000000u);
}
// inverse of f2ord
__device__ __forceinline__ float ord2f(unsigned key) {
    unsigned u = (key & 0x80000000u) ? (key & 0x7fffffffu) : ~key;
    return __uint_as_float(u);
}
// tanh via exp: 1 - 2/(e^{2x}+1).  Selection keys are pre-tanh, so ordering
// is unaffected.
__device__ __forceinline__ float tanh_fast(float x) {
    float e = __expf(2.f * x);
    return 1.f - 2.f / (e + 1.f);
}
// popcount of ballot bits strictly below this lane
__device__ __forceinline__ int mbcnt64(unsigned long long m) {
    return __builtin_amdgcn_mbcnt_hi((unsigned)(m >> 32),
           __builtin_amdgcn_mbcnt_lo((unsigned)m, 0u));
}

// Wave-level exact top-k (order-preserving, stable ties = earliest kept),
// matching stable lax.top_k -> sort(idx) -> gather.  Lane holds contiguous
// chunk [lane*CH, ...) as order-keys in regs; invalid slots MUST be 0
// (0 is below every real key).  Writes tanh(value), original order, to out.
template<int CH>
__device__ void wave_select(const unsigned* keys, int k,
                            float* __restrict__ out)
{
    // ---- exact k-th-largest key via 32-bit MSD radix, ballot counting ----
    unsigned p = 0;
    #pragma unroll 1
    for (int pos = 31; pos >= 0; --pos) {
        const unsigned t = p | (1u << pos);
        int cnt = 0;
        #pragma unroll
        for (int i = 0; i < CH; ++i)
            cnt += __popcll(__ballot(keys[i] >= t));
        if (cnt >= k) p = t;          // wave-uniform (scalar) decision
    }
    const unsigned T = p;

    // ---- stable compaction: per-lane counts + ballot/mbcnt prefix scan ----
    int g = 0, e = 0;
    #pragma unroll
    for (int i = 0; i < CH; ++i) { g += (keys[i] > T); e += (keys[i] == T); }

    int gtBefore = 0, eqBefore = 0, totG = 0;
    #pragma unroll
    for (int b = 0; b < 5; ++b) {     // CH <= 17 < 32 -> 5 bits
        unsigned long long mg = __ballot((g >> b) & 1);
        unsigned long long me = __ballot((e >> b) & 1);
        gtBefore += mbcnt64(mg) << b;
        eqBefore += mbcnt64(me) << b;
        totG     += __popcll(mg) << b;
    }
    const int needTies = k - totG;    // # of ==T to keep (earliest)

    int gRun = 0, eRun = 0;
    #pragma unroll
    for (int i = 0; i < CH; ++i) {
        unsigned key = keys[i];
        if (key > T) {
            int cap = eqBefore + eRun; if (cap > needTies) cap = needTies;
            out[gtBefore + gRun + cap] = tanh_fast(ord2f(key));
            ++gRun;
        } else if (key == T) {
            int eIdx = eqBefore + eRun;
            if (eIdx < needTies) out[gtBefore + gRun + eIdx] = tanh_fast(ord2f(key));
            ++eRun;
        }
    }
}

// ---------------------------------------------------------------------------
// Layer 1 fused: emb gather + pair conv (IPG=1,K=7) + fold + select + tanh.
// grid (32 j, 64 b), block 640 = 10 waves; wave w handles filter f = w.
// ---------------------------------------------------------------------------
__global__ __launch_bounds__(640) void layer1_fused(
    const int* __restrict__ tokens, const float* __restrict__ emb,
    const float* __restrict__ W1, const float* __restrict__ B1,
    float* __restrict__ Z1)
{
    const int j = blockIdx.x;       // 0..31 pair-group
    const int b = blockIdx.y;       // 0..63
    const int t = threadIdx.x;
    const int f = t >> 6;           // 0..9 (wave id = filter)
    const int lane = t & 63;

    __shared__ float xr[2][1036];

    const float2* emb2 = (const float2*)emb;
    for (int i = t; i < 1036; i += 640) {
        int s = i - 6;
        float a = 0.f, c = 0.f;
        if (s >= 0 && s < 1024) {
            int tok = tokens[b * 1024 + s];
            float2 v = emb2[(size_t)tok * 32 + j];
            a = v.x; c = v.y;
        }
        xr[0][i] = a;
        xr[1][i] = c;
    }
    __syncthreads();

    const int beg = lane * 17;
    const int len = max(0, min(17, 1030 - beg));

    float x0[23], x1[23];
    #pragma unroll
    for (int i = 0; i < 23; ++i)
        if (i < len + 6) { x0[i] = xr[0][beg + i]; x1[i] = xr[1][beg + i]; }

    float wa[7], wb[7];
    #pragma unroll
    for (int k2 = 0; k2 < 7; ++k2) {
        wa[k2] = W1[(2 * j * 10 + f) * 7 + k2];
        wb[k2] = W1[((2 * j + 1) * 10 + f) * 7 + k2];
    }
    const float bias = B1[2 * j * 10 + f] + B1[(2 * j + 1) * 10 + f];

    unsigned keys[17];
    #pragma unroll
    for (int i = 0; i < 17; ++i) {
        if (i < len) {
            float acc = bias;
            #pragma unroll
            for (int k2 = 0; k2 < 7; ++k2)
                acc += x0[i + k2] * wa[k2] + x1[i + k2] * wb[k2];
            keys[i] = f2ord(acc);
        } else {
            keys[i] = 0u;
        }
    }
    wave_select<17>(keys, 768,
                    Z1 + ((size_t)(b * 320 + j * 10 + f)) * 768);
}

// ---------------------------------------------------------------------------
// Fused conv + fold + select + tanh (layers 2-4).
// grid (G/2 j, 64 b), block NW*64.  Wave w computes output rows (filters)
// f = 2w, 2w+1 completely (length SOUT), then selects top-KSEL of each.
// LDS: all 2*IPG input rows, zero-padded to width 64*CH+K-1 so the register
// window load is branchless.  Weights are wave-uniform -> scalar s_loads.
// ---------------------------------------------------------------------------
template <int IPG, int NF, int K, int SIN, int SOUT, int KSEL, int NW, int CH>
__global__ __launch_bounds__(NW * 64, 1) void conv_fold_select_kernel(
    const float* __restrict__ X, const float* __restrict__ W,
    const float* __restrict__ Bias, float* __restrict__ Z,
    int Cin, int Cfold)
{
    static_assert(NF == 2 * NW, "2 filters per wave");
    static_assert(64 * CH >= SOUT, "chunk covers row");
    constexpr int W2 = 64 * CH + K - 1;   // padded LDS row width

    const int t = threadIdx.x;
    const int j = blockIdx.x;
    const int b = blockIdx.y;
    const int wav = t >> 6, lane = t & 63;

    __shared__ float xs[2 * IPG][W2];

    const float* Xb = X + ((size_t)b * Cin + (size_t)(2 * j) * IPG) * SIN;
    for (int idx = t; idx < 2 * IPG * W2; idx += NW * 64) {
        int r = idx / W2, p = idx - r * W2;
        int sg = p - (K - 1);
        xs[r][p] = (sg >= 0 && sg < SIN) ? Xb[(size_t)r * SIN + sg] : 0.f;
    }
    __syncthreads();

    const int f0 = __builtin_amdgcn_readfirstlane(2 * wav);
    float acc0[CH], acc1[CH];
    {
        float bias0 = Bias[2 * j * NF + f0]     + Bias[(2 * j + 1) * NF + f0];
        float bias1 = Bias[2 * j * NF + f0 + 1] + Bias[(2 * j + 1) * NF + f0 + 1];
        #pragma unroll
        for (int i = 0; i < CH; ++i) { acc0[i] = bias0; acc1[i] = bias1; }
    }
    const int base = lane * CH;

    #pragma unroll 2
    for (int h = 0; h < 2; ++h) {
        const float* Wh = W + (size_t)((2 * j + h) * NF) * IPG * K;
        #pragma unroll 1
        for (int c = 0; c < IPG; ++c) {
            float win[CH + K - 1];
            #pragma unroll
            for (int p = 0; p < CH + K - 1; ++p)
                win[p] = xs[h * IPG + c][base + p];
            #pragma unroll
            for (int k2 = 0; k2 < K; ++k2) {
                const float w0 = Wh[((size_t)f0 * IPG + c) * K + k2];
                const float w1 = Wh[((size_t)(f0 + 1) * IPG + c) * K + k2];
                #pragma unroll
                for (int i = 0; i < CH; ++i) {
                    acc0[i] = fmaf(win[i + k2], w0, acc0[i]);
                    acc1[i] = fmaf(win[i + k2], w1, acc1[i]);
                }
            }
        }
    }

    const size_t orow = (size_t)b * Cfold + (size_t)j * NF;
    unsigned keys[CH];
    #pragma unroll
    for (int i = 0; i < CH; ++i)
        keys[i] = (base + i < SOUT) ? f2ord(acc0[i]) : 0u;
    wave_select<CH>(keys, KSEL, Z + (orow + f0) * (size_t)KSEL);
    #pragma unroll
    for (int i = 0; i < CH; ++i)
        keys[i] = (base + i < SOUT) ? f2ord(acc1[i]) : 0u;
    wave_select<CH>(keys, KSEL, Z + (orow + f0 + 1) * (size_t)KSEL);
}

// ---------------------------------------------------------------------------
// FC: (64,352) @ (6,352)^T + b
// ---------------------------------------------------------------------------
__global__ __launch_bounds__(192) void fc_kernel(
    const float* __restrict__ Z, const float* __restrict__ Wf,
    const float* __restrict__ bf, float* __restrict__ out)
{
    int g = blockIdx.x * blockDim.x + threadIdx.x;
    if (g >= 64 * 6) return;
    int b = g / 6, c = g % 6;
    float acc = bf[c];
    const float* zr = Z + b * 352;
    const float* wr = Wf + c * 352;
    for (int i = 0; i < 352; ++i) acc += zr[i] * wr[i];
    out[g] = acc;
}

extern "C" void kernel_launch(void* const* d_in, const int* in_sizes, int n_in,
                              void* d_out, int out_size, void* d_ws, size_t ws_size,
                              hipStream_t stream)
{
    const int*   tokens = (const int*)  d_in[0];
    const float* emb    = (const float*)d_in[1];
    const float* w1     = (const float*)d_in[2];
    const float* b1     = (const float*)d_in[3];
    const float* w2     = (const float*)d_in[4];
    const float* b2     = (const float*)d_in[5];
    const float* w3     = (const float*)d_in[6];
    const float* b3     = (const float*)d_in[7];
    const float* w4     = (const float*)d_in[8];
    const float* b4     = (const float*)d_in[9];
    const float* fcw    = (const float*)d_in[10];
    const float* fcb    = (const float*)d_in[11];
    float* out = (float*)d_out;
    float* ws  = (float*)d_ws;

    // workspace layout (floats) — only post-select Z buffers exist now:
    //  Z1 [0,        15728640)   64*320*768  (63 MB)
    //  Z2 [15728640, 23068672)   64*224*512  (29 MB)   peak 92 MB
    //  Z3 [0,         2359296)   64*144*256
    //  Z4 [2359296,   2381824)   64*88*4
    float* Z1 = ws;
    float* Z2 = ws + 15728640;
    float* Z3 = ws;
    float* Z4 = ws + 2359296;

    layer1_fused<<<dim3(32, 64), 640, 0, stream>>>(tokens, emb, w1, b1, Z1);

    // L2: IPG=10 NF=14 K=5  768->772, keep 512.  NW=7, CH=13, LDS 65.3 KB
    conv_fold_select_kernel<10, 14, 5, 768, 772, 512, 7, 13>
        <<<dim3(16, 64), 7 * 64, 0, stream>>>(Z1, w2, b2, Z2, 320, 224);

    // L3: IPG=14 NF=18 K=5  512->516, keep 256.  NW=9, CH=9, LDS 63.4 KB
    conv_fold_select_kernel<14, 18, 5, 512, 516, 256, 9, 9>
        <<<dim3(8, 64), 9 * 64, 0, stream>>>(Z2, w3, b3, Z3, 224, 144);

    // L4: IPG=18 NF=22 K=3  256->258, keep 4.    NW=11, CH=5, LDS 45.3 KB
    conv_fold_select_kernel<18, 22, 3, 256, 258, 4, 11, 5>
        <<<dim3(4, 64), 11 * 64, 0, stream>>>(Z3, w4, b4, Z4, 144, 88);

    fc_kernel<<<2, 192, 0, stream>>>(Z4, fcw, fcb, out);
}

// Round 7
// 380.260 us; speedup vs baseline: 1.7965x; 1.0813x over previous
//
#include <hip/hip_runtime.h>
#include <hip/hip_bf16.h>
#include <math.h>

// ---------------------------------------------------------------------------
// DeepDCNN: emb-gather -> 4x [grouped full-conv + pair-fold + ordered top-k +
// tanh] -> FC.  All fp32.
// Top-k = wave-level bitwise radix select; ballots via
// __builtin_amdgcn_ballot_w64(cmp) so each count step is ONE v_cmp (the HIP
// __ballot(int) wrapper costs 3 VALU ops).  Two rows selected per wave with
// interleaved radix chains for ILP.
// ---------------------------------------------------------------------------

#if defined(__has_builtin)
#if __has_builtin(__builtin_amdgcn_ballot_w64)
#define BALLOT64(expr) __builtin_amdgcn_ballot_w64(expr)
#endif
#endif
#ifndef BALLOT64
#define BALLOT64(expr) __ballot(expr)
#endif

__device__ __forceinline__ unsigned f2ord(float f) {
    unsigned u = __float_as_uint(f);
    return (u & 0x80000000u) ? ~u : (u | 0x80000000u);
}
// inverse of f2ord
__device__ __forceinline__ float ord2f(unsigned key) {
    unsigned u = (key & 0x80000000u) ? (key & 0x7fffffffu) : ~key;
    return __uint_as_float(u);
}
// tanh via exp + hw rcp: 1 - 2*rcp(e^{2x}+1).  |err| ~1e-7, limits exact.
// Selection keys are pre-tanh so ordering is unaffected.
__device__ __forceinline__ float tanh_fast(float x) {
    float e = __expf(2.f * x);
    return 1.f - 2.f * __builtin_amdgcn_rcpf(e + 1.f);
}
// popcount of ballot bits strictly below this lane
__device__ __forceinline__ int mbcnt64(unsigned long long m) {
    return __builtin_amdgcn_mbcnt_hi((unsigned)(m >> 32),
           __builtin_amdgcn_mbcnt_lo((unsigned)m, 0u));
}

// ---- compaction + tanh + scatter-write of kept elements (one row) --------
// T = exact key of k-th largest; stable (earliest ties kept), order-preserving.
template<int CH>
__device__ __forceinline__ void select_finish(const unsigned* keys, unsigned T,
                                              int k, float* __restrict__ out)
{
    int g = 0, e = 0;
    #pragma unroll
    for (int i = 0; i < CH; ++i) { g += (keys[i] > T); e += (keys[i] == T); }

    int gtBefore = 0, eqBefore = 0, totG = 0;
    #pragma unroll
    for (int b = 0; b < 5; ++b) {     // CH <= 17 < 32 -> 5 bits
        unsigned long long mg = BALLOT64((((g >> b) & 1) != 0));
        unsigned long long me = BALLOT64((((e >> b) & 1) != 0));
        gtBefore += mbcnt64(mg) << b;
        eqBefore += mbcnt64(me) << b;
        totG     += __popcll(mg) << b;
    }
    const int needTies = k - totG;    // # of ==T to keep (earliest)

    int gRun = 0, eRun = 0;
    #pragma unroll
    for (int i = 0; i < CH; ++i) {
        const unsigned key = keys[i];
        const bool isG = key > T;
        const bool isE = key == T;
        const int eIdx = eqBefore + eRun;
        const int dst = gtBefore + gRun + min(eIdx, needTies);
        if (isG || (isE && eIdx < needTies))
            out[dst] = tanh_fast(ord2f(key));
        gRun += isG; eRun += isE;
    }
}

// ---- dual-row exact top-k: two independent radix chains interleaved ------
// Lane holds contiguous chunk [lane*CH, ...) of each row as order-keys in
// regs; invalid slots MUST be 0 (below every real key).
template<int CH>
__device__ void wave_select2(const unsigned* k0, const unsigned* k1, int k,
                             float* __restrict__ out0, float* __restrict__ out1)
{
    unsigned p0 = 0, p1 = 0;
    #pragma unroll 1
    for (int pos = 31; pos >= 0; --pos) {
        const unsigned bit = 1u << pos;
        const unsigned t0 = p0 | bit, t1 = p1 | bit;
        int c0 = 0, c1 = 0;
        #pragma unroll
        for (int i = 0; i < CH; ++i) {
            c0 += __popcll(BALLOT64((k0[i] >= t0)));
            c1 += __popcll(BALLOT64((k1[i] >= t1)));
        }
        if (c0 >= k) p0 = t0;         // wave-uniform (scalar) decisions
        if (c1 >= k) p1 = t1;
    }
    select_finish<CH>(k0, p0, k, out0);
    select_finish<CH>(k1, p1, k, out1);
}

// ---------------------------------------------------------------------------
// Layer 1 fused: emb gather + pair conv (IPG=1,K=7) + fold + select + tanh.
// grid (32 j, 64 b), block 320 = 5 waves; wave w handles filters w and w+5
// (dual interleaved select).
// ---------------------------------------------------------------------------
__global__ __launch_bounds__(320) void layer1_fused(
    const int* __restrict__ tokens, const float* __restrict__ emb,
    const float* __restrict__ W1, const float* __restrict__ B1,
    float* __restrict__ Z1)
{
    const int j = blockIdx.x;       // 0..31 pair-group
    const int b = blockIdx.y;       // 0..63
    const int t = threadIdx.x;
    const int w = t >> 6;           // 0..4
    const int lane = t & 63;

    __shared__ float xr[2][1036];

    const float2* emb2 = (const float2*)emb;
    for (int i = t; i < 1036; i += 320) {
        int s = i - 6;
        float a = 0.f, c = 0.f;
        if (s >= 0 && s < 1024) {
            int tok = tokens[b * 1024 + s];
            float2 v = emb2[(size_t)tok * 32 + j];
            a = v.x; c = v.y;
        }
        xr[0][i] = a;
        xr[1][i] = c;
    }
    __syncthreads();

    const int beg = lane * 17;
    const int len = max(0, min(17, 1030 - beg));

    float x0[23], x1[23];
    #pragma unroll
    for (int i = 0; i < 23; ++i)
        if (i < len + 6) { x0[i] = xr[0][beg + i]; x1[i] = xr[1][beg + i]; }

    unsigned keys0[17], keys1[17];
    #pragma unroll 2
    for (int half = 0; half < 2; ++half) {
        const int f = w + 5 * half;
        float wa[7], wb[7];
        #pragma unroll
        for (int k2 = 0; k2 < 7; ++k2) {
            wa[k2] = W1[(2 * j * 10 + f) * 7 + k2];
            wb[k2] = W1[((2 * j + 1) * 10 + f) * 7 + k2];
        }
        const float bias = B1[2 * j * 10 + f] + B1[(2 * j + 1) * 10 + f];
        unsigned* keys = half ? keys1 : keys0;
        #pragma unroll
        for (int i = 0; i < 17; ++i) {
            if (i < len) {
                float acc = bias;
                #pragma unroll
                for (int k2 = 0; k2 < 7; ++k2)
                    acc += x0[i + k2] * wa[k2] + x1[i + k2] * wb[k2];
                keys[i] = f2ord(acc);
            } else {
                keys[i] = 0u;
            }
        }
    }
    const size_t orow = (size_t)b * 320 + (size_t)j * 10;
    wave_select2<17>(keys0, keys1, 768,
                     Z1 + (orow + w) * 768,
                     Z1 + (orow + w + 5) * 768);
}

// ---------------------------------------------------------------------------
// Fused conv + fold + select + tanh (layers 2-4).
// grid (G/2 j, 64 b), block NW*64.  Wave w computes output rows (filters)
// f = 2w, 2w+1 completely (length SOUT), then dual-selects top-KSEL of each.
// LDS: all 2*IPG input rows, zero-padded to width 64*CH+K-1 (branchless
// window loads).  Weights are wave-uniform -> scalar s_loads.
// ---------------------------------------------------------------------------
template <int IPG, int NF, int K, int SIN, int SOUT, int KSEL, int NW, int CH>
__global__ __launch_bounds__(NW * 64, 1) void conv_fold_select_kernel(
    const float* __restrict__ X, const float* __restrict__ W,
    const float* __restrict__ Bias, float* __restrict__ Z,
    int Cin, int Cfold)
{
    static_assert(NF == 2 * NW, "2 filters per wave");
    static_assert(64 * CH >= SOUT, "chunk covers row");
    constexpr int W2 = 64 * CH + K - 1;   // padded LDS row width

    const int t = threadIdx.x;
    const int j = blockIdx.x;
    const int b = blockIdx.y;
    const int wav = t >> 6, lane = t & 63;

    __shared__ float xs[2 * IPG][W2];

    const float* Xb = X + ((size_t)b * Cin + (size_t)(2 * j) * IPG) * SIN;
    for (int idx = t; idx < 2 * IPG * W2; idx += NW * 64) {
        int r = idx / W2, p = idx - r * W2;
        int sg = p - (K - 1);
        xs[r][p] = (sg >= 0 && sg < SIN) ? Xb[(size_t)r * SIN + sg] : 0.f;
    }
    __syncthreads();

    const int f0 = __builtin_amdgcn_readfirstlane(2 * wav);
    float acc0[CH], acc1[CH];
    {
        float bias0 = Bias[2 * j * NF + f0]     + Bias[(2 * j + 1) * NF + f0];
        float bias1 = Bias[2 * j * NF + f0 + 1] + Bias[(2 * j + 1) * NF + f0 + 1];
        #pragma unroll
        for (int i = 0; i < CH; ++i) { acc0[i] = bias0; acc1[i] = bias1; }
    }
    const int base = lane * CH;

    #pragma unroll 2
    for (int h = 0; h < 2; ++h) {
        const float* Wh = W + (size_t)((2 * j + h) * NF) * IPG * K;
        #pragma unroll 1
        for (int c = 0; c < IPG; ++c) {
            float win[CH + K - 1];
            #pragma unroll
            for (int p = 0; p < CH + K - 1; ++p)
                win[p] = xs[h * IPG + c][base + p];
            #pragma unroll
            for (int k2 = 0; k2 < K; ++k2) {
                const float w0 = Wh[((size_t)f0 * IPG + c) * K + k2];
                const float w1 = Wh[((size_t)(f0 + 1) * IPG + c) * K + k2];
                #pragma unroll
                for (int i = 0; i < CH; ++i) {
                    acc0[i] = fmaf(win[i + k2], w0, acc0[i]);
                    acc1[i] = fmaf(win[i + k2], w1, acc1[i]);
                }
            }
        }
    }

    unsigned keys0[CH], keys1[CH];
    #pragma unroll
    for (int i = 0; i < CH; ++i) {
        keys0[i] = (base + i < SOUT) ? f2ord(acc0[i]) : 0u;
        keys1[i] = (base + i < SOUT) ? f2ord(acc1[i]) : 0u;
    }
    const size_t orow = (size_t)b * Cfold + (size_t)j * NF;
    wave_select2<CH>(keys0, keys1, KSEL,
                     Z + (orow + f0) * (size_t)KSEL,
                     Z + (orow + f0 + 1) * (size_t)KSEL);
}

// ---------------------------------------------------------------------------
// FC: (64,352) @ (6,352)^T + b
// ---------------------------------------------------------------------------
__global__ __launch_bounds__(192) void fc_kernel(
    const float* __restrict__ Z, const float* __restrict__ Wf,
    const float* __restrict__ bf, float* __restrict__ out)
{
    int g = blockIdx.x * blockDim.x + threadIdx.x;
    if (g >= 64 * 6) return;
    int b = g / 6, c = g % 6;
    float acc = bf[c];
    const float* zr = Z + b * 352;
    const float* wr = Wf + c * 352;
    for (int i = 0; i < 352; ++i) acc += zr[i] * wr[i];
    out[g] = acc;
}

extern "C" void kernel_launch(void* const* d_in, const int* in_sizes, int n_in,
                              void* d_out, int out_size, void* d_ws, size_t ws_size,
                              hipStream_t stream)
{
    const int*   tokens = (const int*)  d_in[0];
    const float* emb    = (const float*)d_in[1];
    const float* w1     = (const float*)d_in[2];
    const float* b1     = (const float*)d_in[3];
    const float* w2     = (const float*)d_in[4];
    const float* b2     = (const float*)d_in[5];
    const float* w3     = (const float*)d_in[6];
    const float* b3     = (const float*)d_in[7];
    const float* w4     = (const float*)d_in[8];
    const float* b4     = (const float*)d_in[9];
    const float* fcw    = (const float*)d_in[10];
    const float* fcb    = (const float*)d_in[11];
    float* out = (float*)d_out;
    float* ws  = (float*)d_ws;

    // workspace layout (floats) — only post-select Z buffers exist:
    //  Z1 [0,        15728640)   64*320*768  (63 MB)
    //  Z2 [15728640, 23068672)   64*224*512  (29 MB)   peak 92 MB
    //  Z3 [0,         2359296)   64*144*256
    //  Z4 [2359296,   2381824)   64*88*4
    float* Z1 = ws;
    float* Z2 = ws + 15728640;
    float* Z3 = ws;
    float* Z4 = ws + 2359296;

    layer1_fused<<<dim3(32, 64), 320, 0, stream>>>(tokens, emb, w1, b1, Z1);

    // L2: IPG=10 NF=14 K=5  768->772, keep 512.  NW=7, CH=13, LDS 65.3 KB
    conv_fold_select_kernel<10, 14, 5, 768, 772, 512, 7, 13>
        <<<dim3(16, 64), 7 * 64, 0, stream>>>(Z1, w2, b2, Z2, 320, 224);

    // L3: IPG=14 NF=18 K=5  512->516, keep 256.  NW=9, CH=9, LDS 63.4 KB
    conv_fold_select_kernel<14, 18, 5, 512, 516, 256, 9, 9>
        <<<dim3(8, 64), 9 * 64, 0, stream>>>(Z2, w3, b3, Z3, 224, 144);

    // L4: IPG=18 NF=22 K=3  256->258, keep 4.    NW=11, CH=5, LDS 45.3 KB
    conv_fold_select_kernel<18, 22, 3, 256, 258, 4, 11, 5>
        <<<dim3(4, 64), 11 * 64, 0, stream>>>(Z3, w4, b4, Z4, 144, 88);

    fc_kernel<<<2, 192, 0, stream>>>(Z4, fcw, fcb, out);
}